// Round 1
// baseline (226.179 us; speedup 1.0000x reference)
//
#include <hip/hip_runtime.h>

// Radon transform, MI355X. B=4, IMG=256, NA=512.
// Strategy: fp16 image slabs in LDS, horizontal tap-pairs packed as one 4B word
// -> 2 ds_read_b32 per bilinear sample. Block = (batch, angle-group-of-8, row-slab).
// 38.9 KB LDS/block -> 4 blocks/CU = 32 waves/CU. Slab partials atomicAdd'd into
// a pre-zeroed output; slab ownership is an exact ceil-partition of h.

typedef _Float16 f16;
typedef _Float16 f16x2 __attribute__((ext_vector_type(2)));

#define IMG   256
#define NA    512
#define WST   263                 // LDS row stride in 4B words (odd -> bank decorrelation)
#define SROWS 37                  // staged padded rows per slab (32 + margins)
#define LDSW  (SROWS * WST)       // 9731 words = 38,924 B

__global__ __launch_bounds__(1024) void zero_kernel(float4* __restrict__ out) {
    out[blockIdx.x * 1024 + threadIdx.x] = make_float4(0.f, 0.f, 0.f, 0.f);
}

__global__ __launch_bounds__(512, 8) void radon_kernel(const float* __restrict__ img,
                                                       float* __restrict__ out) {
    __shared__ f16x2 lds2[LDSW];
    const int tid = threadIdx.x;
    const int bx  = blockIdx.x;           // 2048 blocks = b(4) x g(64) x q(8)
    const int q   = bx & 7;               // row slab
    const int g   = (bx >> 3) & 63;       // angle group
    const int b   = bx >> 9;              // batch
    const int rbase = (q << 5) - 2;       // first staged image row (pad margin 2)

    // ---- stage slab: word u=(rr,x) holds (P[r][x-2], P[r][x-1]) as fp16x2, P=0 outside image
    const float* im = img + (b << 16);
    for (int u = tid; u < LDSW; u += 512) {
        int rr = u / WST;
        int x  = u - rr * WST;
        int r  = rbase + rr;
        int c0 = x - 2;
        float va = 0.f, vb = 0.f;
        if ((unsigned)r < 256u) {
            const float* rp = im + (r << 8);
            if ((unsigned)c0 < 256u)       va = rp[c0];
            if ((unsigned)(c0 + 1) < 256u) vb = rp[c0 + 1];
        }
        f16x2 h2; h2.x = (f16)va; h2.y = (f16)vb;
        lds2[u] = h2;
    }
    __syncthreads();

    const int   w   = tid & 255;
    const int   sub = tid >> 8;                       // 0..1
    const float xw  = (float)w - 127.5f;
    // slab ownership boundaries in fy; outer slabs extended to cover the zero-padding halo
    const float B0f = (q == 0) ? -1.25f  : (float)(q << 5);
    const float B1f = (q == 7) ? 257.25f : (float)((q << 5) + 32);

    for (int k = 0; k < 4; ++k) {
        const int j = (k << 1) + sub;                 // 0..7
        const int a = g + (j << 6);                   // strided angles for load balance
        float sth, cth;
        sincosf((float)a * 6.1359231515425649e-3f, &sth, &cth);   // theta = a*pi/512

        // fx(h) = Ax + h*s, fy(h) = Ay + h*c  (pixel coords, align_corners=True)
        const float Ax = fmaf(cth, xw, fmaf(sth, -127.5f, 127.5f));
        const float Ay = fmaf(-sth, xw, fmaf(cth, -127.5f, 127.5f));

        // ---- y-ownership interval: exact ceil-partition across slabs (|cth| >= ~3e-8, never 0)
        const float invc = 1.0f / cth;
        float tA = (B0f - Ay) * invc;
        float tB = (B1f - Ay) * invc;
        float ylo = fminf(tA, tB), yhi = fmaxf(tA, tB);
        ylo = fmaxf(fminf(ylo, 400.0f), -400.0f);
        yhi = fmaxf(fminf(yhi, 400.0f), -400.0f);
        int h0 = (int)ceilf(ylo);
        int h1 = (int)ceilf(yhi) - 1;

        // ---- x validity interval (widened by <=1; zero cols in LDS absorb the slack)
        if (sth >= 1e-6f) {
            const float invs = 1.0f / sth;            // slope s >= 0
            float t0 = (-1.0f - Ax) * invs;
            float t1 = (256.0f - Ax) * invs;
            t0 = fmaxf(fminf(t0, 400.0f), -400.0f);
            t1 = fmaxf(fminf(t1, 400.0f), -400.0f);
            h0 = max(h0, (int)floorf(t0));
            h1 = min(h1, (int)ceilf(t1));
        } else if (Ax <= -1.0f || Ax >= 256.0f) {
            h1 = h0 - 1;                              // fx constant & out of range: empty
        }
        h0 = max(h0, 0);
        h1 = min(h1, 255);
        if (h0 > h1) continue;

        const float Ax2 = Ax + 2.0f;                  // LDS col offset (pad 2)
        const float Ayr = Ay - (float)rbase;          // LDS row coords
        float acc = 0.0f;
        float hf  = (float)h0;
        for (int h = h0; h <= h1; ++h) {
            float px  = fmaf(hf, sth, Ax2);           // in [ -0.01, 259.01 ]
            float pyr = fmaf(hf, cth, Ayr);           // in [ 0.7, 35.3 ]
            hf += 1.0f;
            int   xi = (int)px;                       // trunc == floor (>= -0.01 -> 0 w/ zero taps)
            int   rr = (int)pyr;
            float wx = px  - (float)xi;
            float wy = pyr - (float)rr;
            int   e  = rr * WST + xi;
            f16x2 p0 = lds2[e];                       // (v[y][x], v[y][x+1])
            f16x2 p1 = lds2[e + WST];                 // (v[y+1][x], v[y+1][x+1])
            f16   wyh = (f16)wy;
            f16x2 wy2 = {wyh, wyh};
            f16x2 t   = p0 + wy2 * (p1 - p0);         // packed vertical lerp
            float t0f = (float)t.x, t1f = (float)t.y;
            acc += fmaf(wx, t1f - t0f, t0f);          // horizontal lerp, f32 accumulate
        }
        atomicAdd(out + ((b << 17) + (w << 9) + a), acc);   // out[b,0,w,a]
    }
}

extern "C" void kernel_launch(void* const* d_in, const int* in_sizes, int n_in,
                              void* d_out, int out_size, void* d_ws, size_t ws_size,
                              hipStream_t stream) {
    const float* img = (const float*)d_in[0];
    float* out = (float*)d_out;
    // out is poisoned before every call; atomics need zeros
    zero_kernel<<<dim3(128), dim3(1024), 0, stream>>>((float4*)out);
    radon_kernel<<<dim3(2048), dim3(512), 0, stream>>>(img, out);
}